// Round 7
// baseline (959.071 us; speedup 1.0000x reference)
//
#include <hip/hip_runtime.h>
#include <hip/hip_bf16.h>

// GNN message passing: gather(x[src],x[tgt],ef) -> MLP(112->128->128->48) -> scatter-mean.
// R7: FULLY DECOUPLED WAVES. Each wave owns a 32-edge chunk + private 8KB LDS slab;
// gather, L1/L2/L3 (in-place), msg write, segment detect (shfl/ballot), segment reduce,
// atomics -- all wave-local. ZERO __syncthreads after weight staging: waves drift and
// hide each other's gather/atomic latency (R6 paid 3 vmcnt(0)+barrier drains per tile).
// Segments are detected within the 32-edge chunk only; chunk-boundary targets emit one
// extra partial atomic (7.2M vs 5.1M total) -- fine, atomics are sums.
// srt packed into u64 (eid|src<<21|tgt<<38): halves place scatter + gemm srt fetch.
// pk bf16 converts via __float22bfloat162_rn (1 instr / 2 vals vs 4-op manual RNE).

#define NN 100000
#define NE 1600000
#define NF 48
#define TOT 112
#define HID 128
#define NCHUNK 50000  // NE/32

typedef __attribute__((ext_vector_type(8))) short short8;
typedef __attribute__((ext_vector_type(4))) float floatx4;

__device__ __forceinline__ unsigned short f2bf(float f) {
    union { float f; unsigned u; } v; v.f = f;
    unsigned u = v.u;
    return (unsigned short)((u + 0x7FFFu + ((u >> 16) & 1u)) >> 16);  // RNE
}
__device__ __forceinline__ unsigned pk2(float a, float b) {
    __hip_bfloat162 h = __float22bfloat162_rn(make_float2(a, b));
    return *(unsigned*)&h;  // low16 = a, high16 = b
}

// ---- prep: W fp32 [k][n] -> WT bf16 [n][k], k padded to 128
__global__ void prep_kernel(const float* __restrict__ W1, const float* __restrict__ W2,
                            const float* __restrict__ W3,
                            unsigned short* __restrict__ wt1, unsigned short* __restrict__ wt2,
                            unsigned short* __restrict__ wt3) {
    int idx = blockIdx.x * 256 + threadIdx.x;
    if (idx < 16384) {
        int n = idx >> 7, k = idx & 127;
        wt1[idx] = (k < TOT) ? f2bf(W1[k * HID + n]) : (unsigned short)0;
    } else if (idx < 32768) {
        int j = idx - 16384; int n = j >> 7, k = j & 127;
        wt2[j] = f2bf(W2[k * HID + n]);
    } else if (idx < 38912) {
        int j = idx - 32768; int n = j >> 7, k = j & 127;
        wt3[j] = f2bf(W3[k * NF + n]);
    }
}

__global__ void hist_kernel(const int* __restrict__ ei, int* __restrict__ cnt) {
    int e = blockIdx.x * 256 + threadIdx.x;  // NE exact
    atomicAdd(cnt + ei[NE + e], 1);
}

__global__ void scan_kernel(const int* __restrict__ cnt, int* __restrict__ off,
                            int* __restrict__ counter) {
    __shared__ int sd[256];
    __shared__ int sbase;
    int tid = threadIdx.x;
    int n = blockIdx.x * 256 + tid;
    int v = (n < NN) ? cnt[n] : 0;
    sd[tid] = v;
    __syncthreads();
#pragma unroll
    for (int d = 1; d < 256; d <<= 1) {
        int t = (tid >= d) ? sd[tid - d] : 0;
        __syncthreads();
        sd[tid] += t;
        __syncthreads();
    }
    if (tid == 255) sbase = atomicAdd(counter, sd[255]);
    __syncthreads();
    if (n < NN) off[n] = sbase + sd[tid] - v;  // exclusive
}

__global__ void place_kernel(const int* __restrict__ ei, int* __restrict__ off,
                             unsigned long long* __restrict__ srt) {
    int e = blockIdx.x * 256 + threadIdx.x;  // NE exact
    int t = ei[NE + e];
    int p = atomicAdd(off + t, 1);
    srt[p] = (unsigned long long)e | ((unsigned long long)ei[e] << 21) |
             ((unsigned long long)t << 38);
}

// swizzled LDS frag helper: row stride 256B, 16B granules, granule g stored at g^(row&15)
__device__ __forceinline__ const short8* frag_ptr(const unsigned short* base, int row, int s,
                                                  int lane15, int quad) {
    return (const short8*)((const char*)base + row * 256 + (((s * 4 + quad) ^ lane15) << 4));
}

__launch_bounds__(512, 2)
__global__ void gemm_kernel(const float* __restrict__ x, const float* __restrict__ ef,
                            const unsigned long long* __restrict__ srt,
                            const unsigned short* __restrict__ wt1,
                            const unsigned short* __restrict__ wt2,
                            const unsigned short* __restrict__ wt3,
                            const float* __restrict__ b1, const float* __restrict__ b2,
                            float* __restrict__ out_acc) {
    __shared__ __align__(16) unsigned short lw1[128 * 128];  // 32 KB
    __shared__ __align__(16) unsigned short lw2[128 * 128];  // 32 KB
    __shared__ __align__(16) unsigned short lw3[48 * 128];   // 12 KB
    __shared__ __align__(16) unsigned short ea[256 * 128];   // 64 KB: 8 wave-slabs of 32 rows
    __shared__ float lb1[128], lb2[128];

    const int tid = threadIdx.x;
    // ---- stage weights swizzled (once per persistent block)
    const uint4* s1 = (const uint4*)wt1;
    for (int i = tid; i < 2048; i += 512) {
        int n = i >> 4, g = i & 15;
        *(uint4*)((char*)lw1 + n * 256 + ((g ^ (n & 15)) << 4)) = s1[i];
    }
    const uint4* s2 = (const uint4*)wt2;
    for (int i = tid; i < 2048; i += 512) {
        int n = i >> 4, g = i & 15;
        *(uint4*)((char*)lw2 + n * 256 + ((g ^ (n & 15)) << 4)) = s2[i];
    }
    const uint4* s3 = (const uint4*)wt3;
    for (int i = tid; i < 768; i += 512) {
        int n = i >> 4, g = i & 15;
        *(uint4*)((char*)lw3 + n * 256 + ((g ^ (n & 15)) << 4)) = s3[i];
    }
    if (tid < 128) lb1[tid] = b1[tid];
    else if (tid < 256) lb2[tid - 128] = b2[tid - 128];
    __syncthreads();  // the ONLY block-wide barrier

    const int l15 = tid & 15;
    const int q = (tid & 63) >> 4;
    const int ln = tid & 63;
    const int wave = tid >> 6;
    const int sub = ln & 1;           // 2 lanes per edge row
    const int row = ln >> 1;          // local row 0..31
    const int grow = wave * 32 + row; // LDS row (slab-private)
    const int gl15 = grow & 15;
    const int gwid = blockIdx.x * 8 + wave;
    const int gtot = gridDim.x * 8;

    for (int c = gwid; c < NCHUNK; c += gtot) {
        const int e0 = c * 32;
        // ---- gather own slab: lane covers parts p = 2j+sub of edge row `row`
        unsigned long long pk = srt[e0 + row];
        int eid = (int)(pk & 0x1FFFFFull);
        int src = (int)((pk >> 21) & 0x1FFFFull);
        int tgt = (int)(pk >> 38);
        {
            float4 v[14];
#pragma unroll
            for (int j = 0; j < 14; ++j) {
                int p = 2 * j + sub;
                const float4* gp;
                if (p < 12)      gp = (const float4*)(x + 48 * (size_t)src) + p;
                else if (p < 24) gp = (const float4*)(x + 48 * (size_t)tgt) + (p - 12);
                else             gp = (const float4*)(ef + 16 * (size_t)eid) + (p - 24);
                v[j] = *gp;
            }
#pragma unroll
            for (int j = 0; j < 14; ++j) {
                uint2 h = make_uint2(pk2(v[j].x, v[j].y), pk2(v[j].z, v[j].w));
                *(uint2*)((char*)ea + grow * 256 + ((j ^ gl15) << 4) + (sub << 3)) = h;
            }
            *(uint4*)((char*)ea + grow * 256 + (((14 + sub) ^ gl15) << 4)) =
                make_uint4(0u, 0u, 0u, 0u);  // zero-pad cols 112..127
        }
        // ---- segment starts within this chunk (wave-uniform ballot mask)
        int tprev = __shfl_up(tgt, 2);
        int flag = (row == 0) || (tgt != tprev);
        unsigned long long bmask = __ballot(sub == 0 && flag);  // bit 2*row = run start
        // ---- L1, L2 in-place (frags registered before stores; same-wave DS in order)
#pragma unroll
        for (int layer = 0; layer < 2; ++layer) {
            const unsigned short* lw = layer ? lw2 : lw1;
            const float* lb = layer ? lb2 : lb1;
            short8 bf[2][4];
#pragma unroll
            for (int gi = 0; gi < 2; ++gi)
#pragma unroll
                for (int s = 0; s < 4; ++s)
                    bf[gi][s] = *frag_ptr(ea, (wave * 2 + gi) * 16 + l15, s, l15, q);
#pragma unroll
            for (int mt = 0; mt < 8; ++mt) {
                floatx4 a0 = (floatx4){0.f, 0.f, 0.f, 0.f};
                floatx4 a1 = (floatx4){0.f, 0.f, 0.f, 0.f};
#pragma unroll
                for (int s = 0; s < 4; ++s) {
                    short8 a = *frag_ptr(lw, mt * 16 + l15, s, l15, q);
                    a0 = __builtin_amdgcn_mfma_f32_16x16x32_bf16(a, bf[0][s], a0, 0, 0, 0);
                    a1 = __builtin_amdgcn_mfma_f32_16x16x32_bf16(a, bf[1][s], a1, 0, 0, 0);
                }
                int f0 = mt * 16 + q * 4;
                const float4 bv = *(const float4*)(lb + f0);
                uint2 h0 = make_uint2(pk2(fmaxf(a0[0] + bv.x, 0.f), fmaxf(a0[1] + bv.y, 0.f)),
                                      pk2(fmaxf(a0[2] + bv.z, 0.f), fmaxf(a0[3] + bv.w, 0.f)));
                uint2 h1 = make_uint2(pk2(fmaxf(a1[0] + bv.x, 0.f), fmaxf(a1[1] + bv.y, 0.f)),
                                      pk2(fmaxf(a1[2] + bv.z, 0.f), fmaxf(a1[3] + bv.w, 0.f)));
                int gran = 2 * mt + (q >> 1), off8 = (q & 1) << 3;
                *(uint2*)((char*)ea + (wave * 32 + l15) * 256 + ((gran ^ l15) << 4) + off8) = h0;
                *(uint2*)((char*)ea + (wave * 32 + 16 + l15) * 256 + ((gran ^ l15) << 4) + off8) = h1;
            }
        }
        // ---- L3: msg fp32 in-place (h2 dead after frag reads)
        {
            short8 bf[2][4];
#pragma unroll
            for (int gi = 0; gi < 2; ++gi)
#pragma unroll
                for (int s = 0; s < 4; ++s)
                    bf[gi][s] = *frag_ptr(ea, (wave * 2 + gi) * 16 + l15, s, l15, q);
#pragma unroll
            for (int mt = 0; mt < 3; ++mt) {
                floatx4 a0 = (floatx4){0.f, 0.f, 0.f, 0.f};
                floatx4 a1 = (floatx4){0.f, 0.f, 0.f, 0.f};
#pragma unroll
                for (int s = 0; s < 4; ++s) {
                    short8 a = *frag_ptr(lw3, mt * 16 + l15, s, l15, q);
                    a0 = __builtin_amdgcn_mfma_f32_16x16x32_bf16(a, bf[0][s], a0, 0, 0, 0);
                    a1 = __builtin_amdgcn_mfma_f32_16x16x32_bf16(a, bf[1][s], a1, 0, 0, 0);
                }
                int gran = mt * 4 + q;  // fp32 granule, full 16B
                *(float4*)((char*)ea + (wave * 32 + l15) * 256 + ((gran ^ l15) << 4)) =
                    *(float4*)&a0;
                *(float4*)((char*)ea + (wave * 32 + 16 + l15) * 256 + ((gran ^ l15) << 4)) =
                    *(float4*)&a1;
            }
        }
        // ---- per-wave segment reduce + atomics (same-wave DS order: no barrier needed)
        {
            unsigned long long m = bmask;
            int nseg = __popcll(m);
            const int gcol = ln >> 2, coff = (ln & 3) << 2;
            for (int s = 0; s < nseg; ++s) {
                int b = __builtin_ctzll(m); m &= m - 1;
                int start = b >> 1;
                int end = m ? (__builtin_ctzll(m) >> 1) : 32;
                int t = __shfl(tgt, b);
                if (ln < 48) {
                    float acc = 0.f;
                    for (int r = start; r < end; ++r) {
                        int rr = wave * 32 + r;
                        acc += *(const float*)((const char*)ea + rr * 256 +
                                               ((gcol ^ (rr & 15)) << 4) + coff);
                    }
                    atomicAdd(out_acc + 48 * (size_t)t + ln, acc);
                }
            }
        }
        // no barrier: next chunk reuses only this wave's own slab (in-order DS)
    }
}

__global__ void finalize_kernel(const float* __restrict__ x, const int* __restrict__ cnt,
                                const float* __restrict__ b3, float* __restrict__ out) {
    int i = blockIdx.x * 256 + threadIdx.x;  // NN*48 exact
    float c = (float)cnt[i / 48];
    float upd = (c > 0.f) ? (out[i] / c + b3[i % 48]) : 0.f;
    out[i] = x[i] + upd;
}

extern "C" void kernel_launch(void* const* d_in, const int* in_sizes, int n_in,
                              void* d_out, int out_size, void* d_ws, size_t ws_size,
                              hipStream_t stream) {
    const float* x  = (const float*)d_in[0];
    const int*   ei = (const int*)d_in[1];
    const float* ef = (const float*)d_in[2];
    const float* W1 = (const float*)d_in[3];
    const float* b1 = (const float*)d_in[4];
    const float* W2 = (const float*)d_in[5];
    const float* b2 = (const float*)d_in[6];
    const float* W3 = (const float*)d_in[7];
    const float* b3 = (const float*)d_in[8];
    float* out = (float*)d_out;

    char* ws = (char*)d_ws;
    int* cnt     = (int*)ws;                    // 400000 B (pad 409600)
    int* off     = (int*)(ws + 409600);         // 400000 B (pad 409600)
    int* counter = (int*)(ws + 819200);         // 256 B
    unsigned short* wt1 = (unsigned short*)(ws + 819456);
    unsigned short* wt2 = wt1 + 16384;
    unsigned short* wt3 = wt2 + 16384;          // ends ~897 KB
    unsigned long long* srt = (unsigned long long*)(ws + 901120);  // 12.8 MB

    hipMemsetAsync(out, 0, (size_t)out_size * sizeof(float), stream);
    hipMemsetAsync(cnt, 0, (size_t)NN * sizeof(int), stream);
    hipMemsetAsync(counter, 0, sizeof(int), stream);
    prep_kernel<<<152, 256, 0, stream>>>(W1, W2, W3, wt1, wt2, wt3);
    hist_kernel<<<6250, 256, 0, stream>>>(ei, cnt);
    scan_kernel<<<391, 256, 0, stream>>>(cnt, off, counter);
    place_kernel<<<6250, 256, 0, stream>>>(ei, off, srt);
    gemm_kernel<<<256, 512, 0, stream>>>(x, ef, srt, wt1, wt2, wt3, b1, b2, out);
    finalize_kernel<<<NN * NF / 256, 256, 0, stream>>>(x, cnt, b3, out);
}

// Round 8
// 595.396 us; speedup vs baseline: 1.6108x; 1.6108x over previous
//
#include <hip/hip_runtime.h>
#include <hip/hip_bf16.h>

// GNN message passing: gather(x[src],x[tgt],ef) -> MLP(112->128->128->48) -> scatter-mean.
// R8 = R6 gemm structure (transposed MFMA, TILE=256, 8 waves x 32-edge private slabs,
// in-place layers, XOR-swizzled 256B rows, 3 barriers/tile) + u64-packed srt
// (eid|src<<21|tgt<<38; halves place scatter + gemm srt fetch; ltgt filled from the
// gather's own srt read) + __float22bfloat162_rn packed converts (VALU was 40% busy).
// Aux diet: prep fused into hist (one dispatch), cnt+counter share one memset.
// R7 lesson kept: NO barrier-free restructure -- it spilled (VGPR 128 cap, 1.2GB
// scratch re-reads). Barriers keep register liveness short here.

#define NN 100000
#define NE 1600000
#define NF 48
#define TOT 112
#define HID 128
#define TILE 256
#define NTILE 6250  // NE/256

typedef __attribute__((ext_vector_type(8))) short short8;
typedef __attribute__((ext_vector_type(4))) float floatx4;

__device__ __forceinline__ unsigned short f2bf(float f) {
    union { float f; unsigned u; } v; v.f = f;
    unsigned u = v.u;
    return (unsigned short)((u + 0x7FFFu + ((u >> 16) & 1u)) >> 16);  // RNE
}
__device__ __forceinline__ unsigned pk2(float a, float b) {
    __hip_bfloat162 h = __float22bfloat162_rn(make_float2(a, b));
    return *(unsigned*)&h;  // low16 = a, high16 = b
}

// ---- hist (blocks 0..6249) + prep W->WT bf16 (blocks 6250..6401)
__global__ void hist_prep_kernel(const int* __restrict__ ei, int* __restrict__ cnt,
                                 const float* __restrict__ W1, const float* __restrict__ W2,
                                 const float* __restrict__ W3,
                                 unsigned short* __restrict__ wt1,
                                 unsigned short* __restrict__ wt2,
                                 unsigned short* __restrict__ wt3) {
    if (blockIdx.x < NTILE) {
        int e = blockIdx.x * 256 + threadIdx.x;  // NE exact
        atomicAdd(cnt + ei[NE + e], 1);
        return;
    }
    int idx = (blockIdx.x - NTILE) * 256 + threadIdx.x;
    if (idx < 16384) {
        int n = idx >> 7, k = idx & 127;
        wt1[idx] = (k < TOT) ? f2bf(W1[k * HID + n]) : (unsigned short)0;
    } else if (idx < 32768) {
        int j = idx - 16384; int n = j >> 7, k = j & 127;
        wt2[j] = f2bf(W2[k * HID + n]);
    } else if (idx < 38912) {
        int j = idx - 32768; int n = j >> 7, k = j & 127;
        wt3[j] = f2bf(W3[k * NF + n]);
    }
}

// pure block scan + one atomic/block -> exclusive offsets
__global__ void scan_kernel(const int* __restrict__ cnt, int* __restrict__ off,
                            int* __restrict__ counter) {
    __shared__ int sd[256];
    __shared__ int sbase;
    int tid = threadIdx.x;
    int n = blockIdx.x * 256 + tid;
    int v = (n < NN) ? cnt[n] : 0;
    sd[tid] = v;
    __syncthreads();
#pragma unroll
    for (int d = 1; d < 256; d <<= 1) {
        int t = (tid >= d) ? sd[tid - d] : 0;
        __syncthreads();
        sd[tid] += t;
        __syncthreads();
    }
    if (tid == 255) sbase = atomicAdd(counter, sd[255]);
    __syncthreads();
    if (n < NN) off[n] = sbase + sd[tid] - v;  // exclusive
}

__global__ void place_kernel(const int* __restrict__ ei, int* __restrict__ off,
                             unsigned long long* __restrict__ srt) {
    int e = blockIdx.x * 256 + threadIdx.x;  // NE exact
    int t = ei[NE + e];
    int p = atomicAdd(off + t, 1);  // off consumed (dead after this kernel)
    srt[p] = (unsigned long long)e | ((unsigned long long)ei[e] << 21) |
             ((unsigned long long)t << 38);
}

// swizzled LDS frag helper: row stride 256B, 16B granules, granule g stored at g^(row&15)
__device__ __forceinline__ const short8* frag_ptr(const unsigned short* base, int row, int s,
                                                  int lane15, int quad) {
    return (const short8*)((const char*)base + row * 256 + (((s * 4 + quad) ^ lane15) << 4));
}

__launch_bounds__(512, 2)
__global__ void gemm_kernel(const float* __restrict__ x, const float* __restrict__ ef,
                            const unsigned long long* __restrict__ srt,
                            const unsigned short* __restrict__ wt1,
                            const unsigned short* __restrict__ wt2,
                            const unsigned short* __restrict__ wt3,
                            const float* __restrict__ b1, const float* __restrict__ b2,
                            float* __restrict__ out_acc) {
    __shared__ __align__(16) unsigned short lw1[128 * 128];  // 32 KB
    __shared__ __align__(16) unsigned short lw2[128 * 128];  // 32 KB
    __shared__ __align__(16) unsigned short lw3[48 * 128];   // 12 KB
    __shared__ __align__(16) unsigned short ea[TILE * 128];  // 64 KB: E -> h1 -> h2 -> msg
    __shared__ float lb1[128], lb2[128];
    __shared__ int ltgt[TILE];
    __shared__ int seg_start[TILE + 4];
    __shared__ int seg_tgt[TILE];
    __shared__ int nseg;

    const int tid = threadIdx.x;
    // ---- stage weights swizzled (once per persistent block)
    const uint4* s1 = (const uint4*)wt1;
    for (int i = tid; i < 2048; i += 512) {
        int n = i >> 4, g = i & 15;
        *(uint4*)((char*)lw1 + n * 256 + ((g ^ (n & 15)) << 4)) = s1[i];
    }
    const uint4* s2 = (const uint4*)wt2;
    for (int i = tid; i < 2048; i += 512) {
        int n = i >> 4, g = i & 15;
        *(uint4*)((char*)lw2 + n * 256 + ((g ^ (n & 15)) << 4)) = s2[i];
    }
    const uint4* s3 = (const uint4*)wt3;
    for (int i = tid; i < 768; i += 512) {
        int n = i >> 4, g = i & 15;
        *(uint4*)((char*)lw3 + n * 256 + ((g ^ (n & 15)) << 4)) = s3[i];
    }
    if (tid < 128) lb1[tid] = b1[tid];
    else if (tid < 256) lb2[tid - 128] = b2[tid - 128];
    __syncthreads();

    const int l15 = tid & 15;
    const int q = (tid & 63) >> 4;
    const int ln = tid & 63;
    const int wave = tid >> 6;
    const int sub = ln & 1;                  // 2 lanes per edge row
    const int grow = wave * 32 + (ln >> 1);  // tile-local edge row (0..255)
    const int gl15 = grow & 15;

    for (int tile = blockIdx.x; tile < NTILE; tile += gridDim.x) {
        const int e0 = tile * TILE;
        // ---- gather: lane covers parts p = 2j+sub (j=0..13) of edge row `grow`
        {
            unsigned long long pk = srt[e0 + grow];  // both sub-lanes same addr (L1 bcast)
            int eid = (int)(pk & 0x1FFFFFull);
            int src = (int)((pk >> 21) & 0x1FFFFull);
            int tgt = (int)(pk >> 38);
            if (sub == 0) ltgt[grow] = tgt;
            float4 v[14];
#pragma unroll
            for (int j = 0; j < 14; ++j) {
                int p = 2 * j + sub;
                const float4* gp;
                if (p < 12)      gp = (const float4*)(x + 48 * (size_t)src) + p;
                else if (p < 24) gp = (const float4*)(x + 48 * (size_t)tgt) + (p - 12);
                else             gp = (const float4*)(ef + 16 * (size_t)eid) + (p - 24);
                v[j] = *gp;
            }
#pragma unroll
            for (int j = 0; j < 14; ++j) {
                uint2 h = make_uint2(pk2(v[j].x, v[j].y), pk2(v[j].z, v[j].w));
                *(uint2*)((char*)ea + grow * 256 + ((j ^ gl15) << 4) + (sub << 3)) = h;
            }
            // zero-pad cols 112..127: granules 14,15 (one uint4 per lane)
            *(uint4*)((char*)ea + grow * 256 + (((14 + sub) ^ gl15) << 4)) =
                make_uint4(0u, 0u, 0u, 0u);
        }
        // ---- L1, L2 in-place (frags registered before stores; same-wave DS in order)
#pragma unroll
        for (int layer = 0; layer < 2; ++layer) {
            const unsigned short* lw = layer ? lw2 : lw1;
            const float* lb = layer ? lb2 : lb1;
            short8 bf[2][4];
#pragma unroll
            for (int gi = 0; gi < 2; ++gi)
#pragma unroll
                for (int s = 0; s < 4; ++s)
                    bf[gi][s] = *frag_ptr(ea, (wave * 2 + gi) * 16 + l15, s, l15, q);
#pragma unroll
            for (int mt = 0; mt < 8; ++mt) {
                floatx4 a0 = (floatx4){0.f, 0.f, 0.f, 0.f};
                floatx4 a1 = (floatx4){0.f, 0.f, 0.f, 0.f};
#pragma unroll
                for (int s = 0; s < 4; ++s) {
                    short8 a = *frag_ptr(lw, mt * 16 + l15, s, l15, q);
                    a0 = __builtin_amdgcn_mfma_f32_16x16x32_bf16(a, bf[0][s], a0, 0, 0, 0);
                    a1 = __builtin_amdgcn_mfma_f32_16x16x32_bf16(a, bf[1][s], a1, 0, 0, 0);
                }
                int f0 = mt * 16 + q * 4;
                const float4 bv = *(const float4*)(lb + f0);
                uint2 h0 = make_uint2(pk2(fmaxf(a0[0] + bv.x, 0.f), fmaxf(a0[1] + bv.y, 0.f)),
                                      pk2(fmaxf(a0[2] + bv.z, 0.f), fmaxf(a0[3] + bv.w, 0.f)));
                uint2 h1 = make_uint2(pk2(fmaxf(a1[0] + bv.x, 0.f), fmaxf(a1[1] + bv.y, 0.f)),
                                      pk2(fmaxf(a1[2] + bv.z, 0.f), fmaxf(a1[3] + bv.w, 0.f)));
                int gran = 2 * mt + (q >> 1), off8 = (q & 1) << 3;
                *(uint2*)((char*)ea + (wave * 32 + l15) * 256 + ((gran ^ l15) << 4) + off8) = h0;
                *(uint2*)((char*)ea + (wave * 32 + 16 + l15) * 256 + ((gran ^ l15) << 4) + off8) = h1;
            }
        }
        // ---- L3: msg fp32 in-place (h2 dead after frag reads); b3 added in finalize
        {
            short8 bf[2][4];
#pragma unroll
            for (int gi = 0; gi < 2; ++gi)
#pragma unroll
                for (int s = 0; s < 4; ++s)
                    bf[gi][s] = *frag_ptr(ea, (wave * 2 + gi) * 16 + l15, s, l15, q);
#pragma unroll
            for (int mt = 0; mt < 3; ++mt) {
                floatx4 a0 = (floatx4){0.f, 0.f, 0.f, 0.f};
                floatx4 a1 = (floatx4){0.f, 0.f, 0.f, 0.f};
#pragma unroll
                for (int s = 0; s < 4; ++s) {
                    short8 a = *frag_ptr(lw3, mt * 16 + l15, s, l15, q);
                    a0 = __builtin_amdgcn_mfma_f32_16x16x32_bf16(a, bf[0][s], a0, 0, 0, 0);
                    a1 = __builtin_amdgcn_mfma_f32_16x16x32_bf16(a, bf[1][s], a1, 0, 0, 0);
                }
                int gran = mt * 4 + q;  // fp32 granule, full 16B
                *(float4*)((char*)ea + (wave * 32 + l15) * 256 + ((gran ^ l15) << 4)) =
                    *(float4*)&a0;
                *(float4*)((char*)ea + (wave * 32 + 16 + l15) * 256 + ((gran ^ l15) << 4)) =
                    *(float4*)&a1;
            }
        }
        __syncthreads();  // msg + ltgt complete across waves
        // ---- wave 0: enumerate target runs (4 chunks of 64)
        if (wave == 0) {
            int base = 0;
#pragma unroll
            for (int c = 0; c < 4; ++c) {
                int p = c * 64 + ln;
                int t = ltgt[p];
                int flag = (p == 0) || (t != ltgt[p - 1]);
                unsigned long long mask = __ballot(flag);
                int sid = base + __popcll(mask & ((1ull << ln) - 1ull));
                if (flag) { seg_start[sid] = p; seg_tgt[sid] = t; }
                base += __popcll(mask);
            }
            if (ln == 0) { nseg = base; seg_start[base] = TILE; }
        }
        __syncthreads();
        // ---- segment reduce + one atomic per (segment, feature); swizzled msg reads
        if (ln < 48) {
            const int gcol = ln >> 2, coff = (ln & 3) << 2;
            for (int s = wave; s < nseg; s += 8) {
                int a = seg_start[s], bnd = seg_start[s + 1];
                float s0 = 0.f, s1f = 0.f;
                int p = a;
                for (; p + 1 < bnd; p += 2) {
                    s0  += *(const float*)((const char*)ea + p * 256 +
                                           ((gcol ^ (p & 15)) << 4) + coff);
                    s1f += *(const float*)((const char*)ea + (p + 1) * 256 +
                                           ((gcol ^ ((p + 1) & 15)) << 4) + coff);
                }
                if (p < bnd)
                    s0 += *(const float*)((const char*)ea + p * 256 +
                                          ((gcol ^ (p & 15)) << 4) + coff);
                atomicAdd(out_acc + 48 * (size_t)seg_tgt[s] + ln, s0 + s1f);
            }
        }
        __syncthreads();  // reduce done before next tile overwrites ea/ltgt/segs
    }
}

__global__ void finalize_kernel(const float* __restrict__ x, const int* __restrict__ cnt,
                                const float* __restrict__ b3, float* __restrict__ out) {
    int i = blockIdx.x * 256 + threadIdx.x;  // NN*48 exact
    float c = (float)cnt[i / 48];
    float upd = (c > 0.f) ? (out[i] / c + b3[i % 48]) : 0.f;
    out[i] = x[i] + upd;
}

extern "C" void kernel_launch(void* const* d_in, const int* in_sizes, int n_in,
                              void* d_out, int out_size, void* d_ws, size_t ws_size,
                              hipStream_t stream) {
    const float* x  = (const float*)d_in[0];
    const int*   ei = (const int*)d_in[1];
    const float* ef = (const float*)d_in[2];
    const float* W1 = (const float*)d_in[3];
    const float* b1 = (const float*)d_in[4];
    const float* W2 = (const float*)d_in[5];
    const float* b2 = (const float*)d_in[6];
    const float* W3 = (const float*)d_in[7];
    const float* b3 = (const float*)d_in[8];
    float* out = (float*)d_out;

    char* ws = (char*)d_ws;
    int* cnt     = (int*)ws;                    // 400000 B
    int* counter = (int*)(ws + 400000);         // 4 B (zeroed together with cnt)
    int* off     = (int*)(ws + 409600);         // 400000 B
    unsigned short* wt1 = (unsigned short*)(ws + 819456);
    unsigned short* wt2 = wt1 + 16384;
    unsigned short* wt3 = wt2 + 16384;          // ends ~897 KB
    unsigned long long* srt = (unsigned long long*)(ws + 901120);  // 12.8 MB

    hipMemsetAsync(out, 0, (size_t)out_size * sizeof(float), stream);
    hipMemsetAsync(cnt, 0, (size_t)NN * sizeof(int) + 4, stream);
    hist_prep_kernel<<<NTILE + 152, 256, 0, stream>>>(ei, cnt, W1, W2, W3, wt1, wt2, wt3);
    scan_kernel<<<391, 256, 0, stream>>>(cnt, off, counter);
    place_kernel<<<6250, 256, 0, stream>>>(ei, off, srt);
    gemm_kernel<<<256, 512, 0, stream>>>(x, ef, srt, wt1, wt2, wt3, b1, b2, out);
    finalize_kernel<<<NN * NF / 256, 256, 0, stream>>>(x, cnt, b3, out);
}